// Round 14
// baseline (216.949 us; speedup 1.0000x reference)
//
#include <hip/hip_runtime.h>

typedef _Float16 half8 __attribute__((ext_vector_type(8)));
typedef __fp16 pkh2 __attribute__((ext_vector_type(2)));   // cvt_pkrtz result type
typedef float floatx4 __attribute__((ext_vector_type(4)));

#define AS1 __attribute__((address_space(1)))
#define AS3 __attribute__((address_space(3)))

// Problem constants: B=2, T=2048, DM=1024, H=16, DK=64. BT = B*T = 4096 rows.
// Head slabs: reference reshape(b,h,t,d) makes each head a CONTIGUOUS
// [2048][64] slab at (bi*2048 + hi*128)*1024.

// ---------------- phase 1: f32 -> f16 conversion ----------------
__global__ __launch_bounds__(256) void convert_kernel(
    const float* __restrict__ x, const float* __restrict__ wq,
    const float* __restrict__ wk, const float* __restrict__ wv,
    const float* __restrict__ wo,
    _Float16* __restrict__ xb, _Float16* __restrict__ wqkv,
    _Float16* __restrict__ wob)
{
    int i = (blockIdx.x * 256 + threadIdx.x) * 4;
    const float* src; _Float16* dst; int off;
    if (i < 4194304)      { src = x;  dst = xb;            off = i; }
    else if (i < 5242880) { src = wq; dst = wqkv;          off = i - 4194304; }
    else if (i < 6291456) { src = wk; dst = wqkv + 1048576; off = i - 5242880; }
    else if (i < 7340032) { src = wv; dst = wqkv + 2097152; off = i - 6291456; }
    else                  { src = wo; dst = wob;           off = i - 7340032; }
    float4 v = *(const float4*)(src + off);
    union { uint2 u; pkh2 h[2]; } o;
    o.h[0] = __builtin_amdgcn_cvt_pkrtz(v.x, v.y);
    o.h[1] = __builtin_amdgcn_cvt_pkrtz(v.z, v.w);
    *(uint2*)(dst + off) = o.u;
}

// ---------------- phase 2/4: GEMM  out = A @ W^T (+bias) ----------------
// Single-buffered 2-barrier m97 structure; cross-block TLP hides the
// staging drain (v8: in-block dbuf loses a block/CU; v9/v13: more blocks
// via smaller BM wins; v10: smaller BN loses — A-traffic scales with
// col-tile count). QKV & proj both BM=32: grid (128,24)/(128,8), LDS
// 20KB -> 8 blocks/CU capacity, acc 16 VGPR. XCD chunk-swizzle keeps
// each XCD's weight panels L2-resident. For seg==1 (K) the store column
// is XOR-swizzled at 16B-block granularity (block ^= (n>>6)&7) so
// attention can stage K tiles linearly.
template<bool QKV, int BM, int BN>
__global__ __launch_bounds__(256) void gemm_kernel(
    const _Float16* __restrict__ A, const _Float16* __restrict__ W,
    const float* __restrict__ b0, const float* __restrict__ b1,
    const float* __restrict__ b2,
    const float* __restrict__ cosr, const float* __restrict__ sinr,
    _Float16* __restrict__ O0, _Float16* __restrict__ O1,
    _Float16* __restrict__ O2, float* __restrict__ Of)
{
    constexpr int MT   = (BN == 128) ? BM / 32 : BM / 64;  // A frags per wave
    constexpr int AISS = BM / 32;   // A gll issues per wave (8 rows each)
    constexpr int WISS = BN / 32;   // W gll issues per wave
    __shared__ __align__(16) _Float16 As[BM * 64];
    __shared__ __align__(16) _Float16 Bs[BN * 64];
    const int tid  = threadIdx.x;
    const int lane = tid & 63, w = tid >> 6;
    const int lrow = lane & 15, quad = lane >> 4;
    const int wr = (BN == 128) ? (w & 1) * (BM / 2) : w * (BM / 4);
    const int wc = (BN == 128) ? (w >> 1) * 64 : 0;

    // XCD chunk-swizzle (bijective; grid size divisible by 8):
    const int nwg  = gridDim.x * gridDim.y;
    const int flat = blockIdx.y * gridDim.x + blockIdx.x;
    const int idx  = (flat & 7) * (nwg >> 3) + (flat >> 3);
    const int bx   = idx % gridDim.x;
    const int by   = idx / gridDim.x;

    const int arow0 = bx * BM;
    const int brow0 = by * BN;

    const int r8 = lane >> 3;                 // row within 8-row group
    const int gcol = ((lane & 7) ^ r8) * 8;   // swizzled global column (halfs)

    floatx4 acc[MT][4] = {};

    for (int kk = 0; kk < 1024; kk += 64) {
        __syncthreads();   // previous compute done reading LDS
        for (int u = 0; u < AISS; u++) {
            const int row = w * (8 * AISS) + u * 8;
            __builtin_amdgcn_global_load_lds(
                (const AS1 unsigned*)(const void*)(A + (size_t)(arow0 + row + r8) * 1024 + kk + gcol),
                (AS3 unsigned*)(void*)(As + row * 64), 16, 0, 0);
        }
        for (int u = 0; u < WISS; u++) {
            const int row = w * (8 * WISS) + u * 8;
            __builtin_amdgcn_global_load_lds(
                (const AS1 unsigned*)(const void*)(W + (size_t)(brow0 + row + r8) * 1024 + kk + gcol),
                (AS3 unsigned*)(void*)(Bs + row * 64), 16, 0, 0);
        }
        __syncthreads();   // vmcnt(0) drain inserted by compiler
        for (int ks = 0; ks < 2; ks++) {
            const int swz = ((ks * 4 + quad) ^ (lrow & 7)) * 8;
            half8 af[MT], bf[4];
            for (int mt = 0; mt < MT; mt++)
                af[mt] = *(const half8*)&As[(wr + mt * 16 + lrow) * 64 + swz];
            for (int nt = 0; nt < 4; nt++)
                bf[nt] = *(const half8*)&Bs[(wc + nt * 16 + lrow) * 64 + swz];
            for (int mt = 0; mt < MT; mt++)
                for (int nt = 0; nt < 4; nt++)
                    acc[mt][nt] = __builtin_amdgcn_mfma_f32_16x16x32_f16(
                        af[mt], bf[nt], acc[mt][nt], 0, 0, 0);
        }
    }

    if (QKV) {
        constexpr int CTS = 1024 / BN;   // col-tiles per segment
        const int seg = by / CTS;        // 0=Q 1=K 2=V
        const float* bias = seg == 0 ? b0 : (seg == 1 ? b1 : b2);
        _Float16* out = seg == 0 ? O0 : (seg == 1 ? O1 : O2);
        const int nbase = (by % CTS) * BN + wc;
        for (int nt = 0; nt < 4; nt++) {
            const int n = nbase + nt * 16 + lrow;
            const float bv = bias[n];
            const int dj = n & 63;
            const float cv = cosr[dj], sv = sinr[dj];
            const bool odd = (n & 1) != 0;
            // K storage swizzle: 16B block (bits 3..5 of n) ^= (n>>6)&7
            const int ns = (seg == 1)
                ? ((n & ~56) | ((((n >> 3) ^ (n >> 6)) & 7) << 3))
                : n;
            for (int mt = 0; mt < MT; mt++)
                for (int r = 0; r < 4; r++) {
                    float v = acc[mt][nt][r] + bv;
                    if (seg < 2) {
                        float p = __shfl_xor(v, 1, 64);
                        v = odd ? (v * cv + p * sv) : (v * cv - p * sv);
                    }
                    if (seg == 0) v *= 0.125f;
                    int row = arow0 + wr + mt * 16 + quad * 4 + r;
                    out[row * 1024 + ns] = (_Float16)v;
                }
        }
    } else {
        const int nbase = by * BN + wc;
        for (int nt = 0; nt < 4; nt++) {
            const int n = nbase + nt * 16 + lrow;
            const float bv = b0[n];
            for (int mt = 0; mt < MT; mt++)
                for (int r = 0; r < 4; r++) {
                    int row = arow0 + wr + mt * 16 + quad * 4 + r;
                    Of[row * 1024 + n] = acc[mt][nt][r] + bv;
                }
        }
    }
}

// ---------------- phase 2.5: one-shot V transpose ----------------
// V head chunk [2048][64] -> VT[bh][64][2048], with the key dimension
// XOR-swizzled per 16B block within each 64-key tile: block ^= d&7.
__global__ __launch_bounds__(256) void vtrans_kernel(
    const _Float16* __restrict__ V, _Float16* __restrict__ VT)
{
    __shared__ __align__(16) _Float16 T[64][72];
    const int tid = threadIdx.x;
    const int kt = blockIdx.x;      // 64-key chunk (0..31)
    const int bh = blockIdx.y;      // 0..31
    const int bi = bh >> 4, hi = bh & 15;
    const _Float16* Vh = V + (size_t)(bi * 2048 + hi * 128) * 1024 + kt * 4096;
    const int srow = tid >> 3, sblk = tid & 7;
    union { uint4 u; _Float16 h[8]; } a, b;
    a.u = *(const uint4*)(Vh + (2 * srow) * 64 + sblk * 8);
    b.u = *(const uint4*)(Vh + (2 * srow + 1) * 64 + sblk * 8);
    for (int j = 0; j < 8; j++) {
        union { unsigned u; _Float16 h[2]; } pk;
        pk.h[0] = a.h[j]; pk.h[1] = b.h[j];
        *(unsigned*)&T[sblk * 8 + j][2 * srow] = pk.u;
    }
    __syncthreads();
    const int d = tid >> 2, c = tid & 3;
    const int xr = d & 7;
    _Float16* outrow = VT + ((size_t)bh * 64 + d) * 2048 + kt * 64;
    *(uint4*)(outrow + ((2 * c)     ^ xr) * 8) = *(const uint4*)&T[d][c * 16];
    *(uint4*)(outrow + ((2 * c + 1) ^ xr) * 8) = *(const uint4*)&T[d][c * 16 + 8];
}

// P^T fragment assembly via permlane32_swap + permlane16_swap (v5-proven):
// r = {s16x[0], s16y[0], s16x[1], s16y[1]} = keys quad*8+0..7.
static __device__ __forceinline__ half8 assemble_p(uint2 a, uint2 b) {
    auto s32x = __builtin_amdgcn_permlane32_swap(a.x, b.x, false, false);
    auto s32y = __builtin_amdgcn_permlane32_swap(a.y, b.y, false, false);
    auto s16x = __builtin_amdgcn_permlane16_swap(s32x[0], s32x[1], false, false);
    auto s16y = __builtin_amdgcn_permlane16_swap(s32y[0], s32y[1], false, false);
    union { uint4 u; half8 h; } r;
    r.u.x = s16x[0];   // j0,j1
    r.u.y = s16y[0];   // j2,j3
    r.u.z = s16x[1];   // j4,j5
    r.u.w = s16y[1];   // j6,j7
    return r.h;
}

// ---------------- phase 3: flash attention, v7 (measured best: 47.5us) ----
// 512-thr blocks = two 4-wave KV-split groups; KVBLK=64, permlane P^T
// assembly, gll double-buffered K/V staging (zero staging VGPRs), one
// barrier per k-tile, setprio around MFMA clusters. 16 waves/CU.
__global__ __launch_bounds__(512, 4) void attn_kernel(
    const _Float16* __restrict__ Q, const _Float16* __restrict__ K,
    const _Float16* __restrict__ VT, _Float16* __restrict__ O)
{
    // per group: Ks[2][4096] | Vts[2][4096] = 16384 halfs; x2 groups = 64KB.
    // epilogue overlay: X 16384 halfs | L 2048 | Es 9216 -> 26624 <= 32768.
    __shared__ __align__(16) _Float16 smem[32768];

    const int tid  = threadIdx.x;
    const int g    = tid >> 8;            // KV-split group
    const int wg   = tid >> 6;            // global wave 0..7
    const int w    = wg & 3;              // wave within group
    const int lane = tid & 63;
    const int lrow = lane & 15, quad = lane >> 4;

    // XCD grouping: all 16 q-tiles of a head land on one XCD (4 heads/XCD)
    const int bid = blockIdx.x;
    const int bh  = (bid & 7) * 4 + (bid >> 7);
    const int qt  = (bid >> 3) & 15;
    const int bi = bh >> 4, hi = bh & 15;
    const size_t base = (size_t)(bi * 2048 + hi * 128) * 1024;
    const _Float16* Qh  = Q + base;
    const _Float16* Kh  = K + base + (size_t)g * 65536;          // +1024 keys
    const _Float16* VTh = VT + (size_t)bh * 131072 + g * 1024;   // +1024 keys

    _Float16* Ks0  = smem + g * 16384;          // [2][64][64]
    _Float16* Vts0 = smem + g * 16384 + 8192;   // [2][64][64]  ([d][key])

    // Q fragments: qrow = qt*128 + w*32 + nt*16 + lrow
    half8 qf[2][2];
    for (int nt = 0; nt < 2; nt++)
        for (int ks = 0; ks < 2; ks++)
            qf[nt][ks] = *(const half8*)(Qh + (qt * 128 + w * 32 + nt * 16 + lrow) * 64
                                          + ks * 32 + quad * 8);

    floatx4 oacc[4][2] = {};   // [dt][nt], O^T C-layout
    float lsum0 = 0.0f, lsum1 = 0.0f;

    // gll lane-linear staging sources (global images are pre-swizzled):
    const _Float16* klsrc = Kh + w * 1024 + lane * 8;
    const _Float16* vlsrc = VTh + (size_t)(w * 16 + (lane >> 3)) * 2048 + (lane & 7) * 8;

    auto stage = [&](int kt, int b) {
        const _Float16* ks = klsrc + kt * 4096;
        _Float16* kd = Ks0 + b * 4096 + w * 1024;
        __builtin_amdgcn_global_load_lds((const AS1 unsigned*)(const void*)ks,
                                         (AS3 unsigned*)(void*)kd, 16, 0, 0);
        __builtin_amdgcn_global_load_lds((const AS1 unsigned*)(const void*)(ks + 512),
                                         (AS3 unsigned*)(void*)(kd + 512), 16, 0, 0);
        const _Float16* vs = vlsrc + kt * 64;
        _Float16* vd = Vts0 + b * 4096 + w * 1024;
        __builtin_amdgcn_global_load_lds((const AS1 unsigned*)(const void*)vs,
                                         (AS3 unsigned*)(void*)vd, 16, 0, 0);
        __builtin_amdgcn_global_load_lds((const AS1 unsigned*)(const void*)(vs + 8 * 2048),
                                         (AS3 unsigned*)(void*)(vd + 512), 16, 0, 0);
    };

    const float LOG2E = 1.44269504f;
    const float OFF   = -8.65617025f;   // -6 * log2(e): p = e^(s-6)

    // preamble: stage tile 0 into buffer 0
    stage(0, 0);
    __syncthreads();   // vmcnt(0) drain -> buf0 ready

    for (int ktl = 0; ktl < 16; ktl++) {
        const int cur = ktl & 1;
        if (ktl < 15) stage(ktl + 1, cur ^ 1);   // in flight during compute
        const _Float16* Ksg  = Ks0 + cur * 4096;
        const _Float16* Vtsg = Vts0 + cur * 4096;
        for (int h = 0; h < 2; h++) {
            union { uint2 u; pkh2 h2[2]; } pA[2], pB[2];   // [k2]
            for (int k2 = 0; k2 < 2; k2++) {          // 16-key subtile
                const int kt4 = h * 2 + k2;
                floatx4 s0 = {}, s1 = {};
                __builtin_amdgcn_s_setprio(1);
                for (int ks = 0; ks < 2; ks++) {
                    half8 af = *(const half8*)&Ksg[(kt4 * 16 + lrow) * 64
                                 + (((ks * 4 + quad) ^ (lrow & 7)) * 8)];
                    s0 = __builtin_amdgcn_mfma_f32_16x16x32_f16(af, qf[0][ks], s0, 0, 0, 0);
                    s1 = __builtin_amdgcn_mfma_f32_16x16x32_f16(af, qf[1][ks], s1, 0, 0, 0);
                }
                __builtin_amdgcn_s_setprio(0);
                float p00 = __builtin_amdgcn_exp2f(fmaf(s0[0], LOG2E, OFF));
                float p01 = __builtin_amdgcn_exp2f(fmaf(s0[1], LOG2E, OFF));
                float p02 = __builtin_amdgcn_exp2f(fmaf(s0[2], LOG2E, OFF));
                float p03 = __builtin_amdgcn_exp2f(fmaf(s0[3], LOG2E, OFF));
                float p10 = __builtin_amdgcn_exp2f(fmaf(s1[0], LOG2E, OFF));
                float p11 = __builtin_amdgcn_exp2f(fmaf(s1[1], LOG2E, OFF));
                float p12 = __builtin_amdgcn_exp2f(fmaf(s1[2], LOG2E, OFF));
                float p13 = __builtin_amdgcn_exp2f(fmaf(s1[3], LOG2E, OFF));
                lsum0 += (p00 + p01) + (p02 + p03);
                lsum1 += (p10 + p11) + (p12 + p13);
                pA[k2].h2[0] = __builtin_amdgcn_cvt_pkrtz(p00, p01);
                pA[k2].h2[1] = __builtin_amdgcn_cvt_pkrtz(p02, p03);
                pB[k2].h2[0] = __builtin_amdgcn_cvt_pkrtz(p10, p11);
                pB[k2].h2[1] = __builtin_amdgcn_cvt_pkrtz(p12, p13);
            }
            // in-register P^T fragment assembly
            half8 bf0 = assemble_p(pA[0].u, pA[1].u);
            half8 bf1 = assemble_p(pB[0].u, pB[1].u);
            // O^T += V^T . P^T for this 32-key half
            __builtin_amdgcn_s_setprio(1);
            for (int dt = 0; dt < 4; dt++) {
                half8 av = *(const half8*)&Vtsg[(dt * 16 + lrow) * 64
                              + (((h * 4 + quad) ^ (lrow & 7)) * 8)];
                oacc[dt][0] = __builtin_amdgcn_mfma_f32_16x16x32_f16(av, bf0, oacc[dt][0], 0, 0, 0);
                oacc[dt][1] = __builtin_amdgcn_mfma_f32_16x16x32_f16(av, bf1, oacc[dt][1], 0, 0, 0);
            }
            __builtin_amdgcn_s_setprio(0);
        }
        __syncthreads();   // drains next-tile gll; frees buf cur for ktl+2
    }

    // ---- combine the two key-halves through LDS ----
    // X: [8 chunks][4 w][64 lane][4 f32] = 32KB over smem[0..16384) halfs.
    float* X = (float*)smem;
    float* L = (float*)(smem + 16384);   // 512 f32
    if (g == 1) {
        for (int dt = 0; dt < 4; dt++)
            for (int nt = 0; nt < 2; nt++)
                *(floatx4*)&X[((dt * 2 + nt) * 256 + w * 64 + lane) * 4] = oacc[dt][nt];
        L[(w * 64 + lane) * 2]     = lsum0;
        L[(w * 64 + lane) * 2 + 1] = lsum1;
    }
    __syncthreads();
    if (g == 0) {
        for (int dt = 0; dt < 4; dt++)
            for (int nt = 0; nt < 2; nt++)
                oacc[dt][nt] += *(const floatx4*)&X[((dt * 2 + nt) * 256 + w * 64 + lane) * 4];
        lsum0 += L[(w * 64 + lane) * 2];
        lsum1 += L[(w * 64 + lane) * 2 + 1];
        // reduce l over quads, normalize, transpose O^T -> O via LDS
        lsum0 += __shfl_xor(lsum0, 16, 64); lsum0 += __shfl_xor(lsum0, 32, 64);
        lsum1 += __shfl_xor(lsum1, 16, 64); lsum1 += __shfl_xor(lsum1, 32, 64);
        const float inv0 = 1.0f / lsum0, inv1 = 1.0f / lsum1;
        _Float16* Es = smem + 17408 + w * 2304;   // 32 rows x 72 per wave
        for (int dt = 0; dt < 4; dt++) {
            union { uint2 u; pkh2 h2[2]; } a0, a1;
            a0.h2[0] = __builtin_amdgcn_cvt_pkrtz(oacc[dt][0][0] * inv0, oacc[dt][0][1] * inv0);
            a0.h2[1] = __builtin_amdgcn_cvt_pkrtz(oacc[dt][0][2] * inv0, oacc[dt][0][3] * inv0);
            a1.h2[0] = __builtin_amdgcn_cvt_pkrtz(oacc[dt][1][0] * inv1, oacc[dt][1][1] * inv1);
            a1.h2[1] = __builtin_amdgcn_cvt_pkrtz(oacc[dt][1][2] * inv1, oacc[dt][1][3] * inv1);
            *(uint2*)&Es[lrow * 72 + dt * 16 + quad * 4]        = a0.u;
            *(uint2*)&Es[(16 + lrow) * 72 + dt * 16 + quad * 4] = a1.u;
        }
        const int rw = lane >> 1, hf = lane & 1;
        const size_t orow = (size_t)(bi * 2048 + qt * 128 + w * 32 + rw) * 1024
                            + hi * 64 + hf * 32;
        for (int i = 0; i < 4; i++)
            *(uint4*)(O + orow + i * 8) = *(const uint4*)&Es[rw * 72 + hf * 32 + i * 8];
    }
}

extern "C" void kernel_launch(void* const* d_in, const int* in_sizes, int n_in,
                              void* d_out, int out_size, void* d_ws, size_t ws_size,
                              hipStream_t stream) {
    const float* x    = (const float*)d_in[0];
    const float* wq   = (const float*)d_in[1];
    const float* bq   = (const float*)d_in[2];
    const float* wk   = (const float*)d_in[3];
    const float* bk   = (const float*)d_in[4];
    const float* wv   = (const float*)d_in[5];
    const float* bv   = (const float*)d_in[6];
    const float* wo   = (const float*)d_in[7];
    const float* bo   = (const float*)d_in[8];
    const float* cosT = (const float*)d_in[9];   // [3200][64]
    const float* sinT = (const float*)d_in[10];

    _Float16* ws   = (_Float16*)d_ws;
    _Float16* xb   = ws;                  // 4,194,304 (dead after qkv GEMM)
    _Float16* wqkv = xb + 4194304;        // 3,145,728 (wq|wk|wv)
    _Float16* wob  = wqkv + 3145728;      // 1,048,576
    _Float16* Qb   = wob + 1048576;       // 4,194,304
    _Float16* Kb   = Qb + 4194304;        // 4,194,304 (stored block-swizzled)
    _Float16* Vb   = Kb + 4194304;        // 4,194,304
    _Float16* Ob   = Vb + 4194304;        // 4,194,304  (total ~48 MB)
    _Float16* VTb  = xb;                  // aliases xb (consumed before vtrans)

    convert_kernel<<<8192, 256, 0, stream>>>(x, wq, wk, wv, wo, xb, wqkv, wob);
    // reference indexes cos/sin at row t=2048 (broadcast over all positions)
    gemm_kernel<true, 32, 128><<<dim3(128, 24), 256, 0, stream>>>(
        xb, wqkv, bq, bk, bv, cosT + 2048 * 64, sinT + 2048 * 64,
        Qb, Kb, Vb, nullptr);
    vtrans_kernel<<<dim3(32, 32), 256, 0, stream>>>(Vb, VTb);
    attn_kernel<<<dim3(512), 512, 0, stream>>>(Qb, Kb, VTb, Ob);
    gemm_kernel<false, 32, 128><<<dim3(128, 8), 256, 0, stream>>>(
        Ob, wob, bo, nullptr, nullptr, nullptr, nullptr,
        nullptr, nullptr, nullptr, (float*)d_out);
}

// Round 15
// 205.056 us; speedup vs baseline: 1.0580x; 1.0580x over previous
//
#include <hip/hip_runtime.h>

typedef _Float16 half8 __attribute__((ext_vector_type(8)));
typedef __fp16 pkh2 __attribute__((ext_vector_type(2)));   // cvt_pkrtz result type
typedef float floatx4 __attribute__((ext_vector_type(4)));

#define AS1 __attribute__((address_space(1)))
#define AS3 __attribute__((address_space(3)))

// Problem constants: B=2, T=2048, DM=1024, H=16, DK=64. BT = B*T = 4096 rows.
// Head slabs: reference reshape(b,h,t,d) makes each head a CONTIGUOUS
// [2048][64] slab at (bi*2048 + hi*128)*1024.

// ---------------- phase 1: f32 -> f16 conversion ----------------
__global__ __launch_bounds__(256) void convert_kernel(
    const float* __restrict__ x, const float* __restrict__ wq,
    const float* __restrict__ wk, const float* __restrict__ wv,
    const float* __restrict__ wo,
    _Float16* __restrict__ xb, _Float16* __restrict__ wqkv,
    _Float16* __restrict__ wob)
{
    int i = (blockIdx.x * 256 + threadIdx.x) * 4;
    const float* src; _Float16* dst; int off;
    if (i < 4194304)      { src = x;  dst = xb;            off = i; }
    else if (i < 5242880) { src = wq; dst = wqkv;          off = i - 4194304; }
    else if (i < 6291456) { src = wk; dst = wqkv + 1048576; off = i - 5242880; }
    else if (i < 7340032) { src = wv; dst = wqkv + 2097152; off = i - 6291456; }
    else                  { src = wo; dst = wob;           off = i - 7340032; }
    float4 v = *(const float4*)(src + off);
    union { uint2 u; pkh2 h[2]; } o;
    o.h[0] = __builtin_amdgcn_cvt_pkrtz(v.x, v.y);
    o.h[1] = __builtin_amdgcn_cvt_pkrtz(v.z, v.w);
    *(uint2*)(dst + off) = o.u;
}

// ---------------- phase 2/4: GEMM  out = A @ W^T (+bias) ----------------
// Single-buffered 2-barrier m97 structure; cross-block TLP hides the
// staging drain. Measured tile optima (both directions probed):
//   QKV:  BM=64/BN=128, grid (64,24)  — BM=32 thrashes L2 (v14: FETCH 97MB)
//   proj: BM=32/BN=128, grid (128,8)  — grid was its occupancy limit (v13)
// XCD chunk-swizzle keeps each XCD's weight panels L2-resident. For
// seg==1 (K) the store column is XOR-swizzled at 16B-block granularity
// (block ^= (n>>6)&7) so attention can stage K tiles linearly.
template<bool QKV, int BM, int BN>
__global__ __launch_bounds__(256) void gemm_kernel(
    const _Float16* __restrict__ A, const _Float16* __restrict__ W,
    const float* __restrict__ b0, const float* __restrict__ b1,
    const float* __restrict__ b2,
    const float* __restrict__ cosr, const float* __restrict__ sinr,
    _Float16* __restrict__ O0, _Float16* __restrict__ O1,
    _Float16* __restrict__ O2, float* __restrict__ Of)
{
    constexpr int MT   = (BN == 128) ? BM / 32 : BM / 64;  // A frags per wave
    constexpr int AISS = BM / 32;   // A gll issues per wave (8 rows each)
    constexpr int WISS = BN / 32;   // W gll issues per wave
    __shared__ __align__(16) _Float16 As[BM * 64];
    __shared__ __align__(16) _Float16 Bs[BN * 64];
    const int tid  = threadIdx.x;
    const int lane = tid & 63, w = tid >> 6;
    const int lrow = lane & 15, quad = lane >> 4;
    const int wr = (BN == 128) ? (w & 1) * (BM / 2) : w * (BM / 4);
    const int wc = (BN == 128) ? (w >> 1) * 64 : 0;

    // XCD chunk-swizzle (bijective; grid size divisible by 8):
    const int nwg  = gridDim.x * gridDim.y;
    const int flat = blockIdx.y * gridDim.x + blockIdx.x;
    const int idx  = (flat & 7) * (nwg >> 3) + (flat >> 3);
    const int bx   = idx % gridDim.x;
    const int by   = idx / gridDim.x;

    const int arow0 = bx * BM;
    const int brow0 = by * BN;

    const int r8 = lane >> 3;                 // row within 8-row group
    const int gcol = ((lane & 7) ^ r8) * 8;   // swizzled global column (halfs)

    floatx4 acc[MT][4] = {};

    for (int kk = 0; kk < 1024; kk += 64) {
        __syncthreads();   // previous compute done reading LDS
        for (int u = 0; u < AISS; u++) {
            const int row = w * (8 * AISS) + u * 8;
            __builtin_amdgcn_global_load_lds(
                (const AS1 unsigned*)(const void*)(A + (size_t)(arow0 + row + r8) * 1024 + kk + gcol),
                (AS3 unsigned*)(void*)(As + row * 64), 16, 0, 0);
        }
        for (int u = 0; u < WISS; u++) {
            const int row = w * (8 * WISS) + u * 8;
            __builtin_amdgcn_global_load_lds(
                (const AS1 unsigned*)(const void*)(W + (size_t)(brow0 + row + r8) * 1024 + kk + gcol),
                (AS3 unsigned*)(void*)(Bs + row * 64), 16, 0, 0);
        }
        __syncthreads();   // vmcnt(0) drain inserted by compiler
        for (int ks = 0; ks < 2; ks++) {
            const int swz = ((ks * 4 + quad) ^ (lrow & 7)) * 8;
            half8 af[MT], bf[4];
            for (int mt = 0; mt < MT; mt++)
                af[mt] = *(const half8*)&As[(wr + mt * 16 + lrow) * 64 + swz];
            for (int nt = 0; nt < 4; nt++)
                bf[nt] = *(const half8*)&Bs[(wc + nt * 16 + lrow) * 64 + swz];
            for (int mt = 0; mt < MT; mt++)
                for (int nt = 0; nt < 4; nt++)
                    acc[mt][nt] = __builtin_amdgcn_mfma_f32_16x16x32_f16(
                        af[mt], bf[nt], acc[mt][nt], 0, 0, 0);
        }
    }

    if (QKV) {
        constexpr int CTS = 1024 / BN;   // col-tiles per segment
        const int seg = by / CTS;        // 0=Q 1=K 2=V
        const float* bias = seg == 0 ? b0 : (seg == 1 ? b1 : b2);
        _Float16* out = seg == 0 ? O0 : (seg == 1 ? O1 : O2);
        const int nbase = (by % CTS) * BN + wc;
        for (int nt = 0; nt < 4; nt++) {
            const int n = nbase + nt * 16 + lrow;
            const float bv = bias[n];
            const int dj = n & 63;
            const float cv = cosr[dj], sv = sinr[dj];
            const bool odd = (n & 1) != 0;
            // K storage swizzle: 16B block (bits 3..5 of n) ^= (n>>6)&7
            const int ns = (seg == 1)
                ? ((n & ~56) | ((((n >> 3) ^ (n >> 6)) & 7) << 3))
                : n;
            for (int mt = 0; mt < MT; mt++)
                for (int r = 0; r < 4; r++) {
                    float v = acc[mt][nt][r] + bv;
                    if (seg < 2) {
                        float p = __shfl_xor(v, 1, 64);
                        v = odd ? (v * cv + p * sv) : (v * cv - p * sv);
                    }
                    if (seg == 0) v *= 0.125f;
                    int row = arow0 + wr + mt * 16 + quad * 4 + r;
                    out[row * 1024 + ns] = (_Float16)v;
                }
        }
    } else {
        const int nbase = by * BN + wc;
        for (int nt = 0; nt < 4; nt++) {
            const int n = nbase + nt * 16 + lrow;
            const float bv = b0[n];
            for (int mt = 0; mt < MT; mt++)
                for (int r = 0; r < 4; r++) {
                    int row = arow0 + wr + mt * 16 + quad * 4 + r;
                    Of[row * 1024 + n] = acc[mt][nt][r] + bv;
                }
        }
    }
}

// ---------------- phase 2.5: one-shot V transpose ----------------
// V head chunk [2048][64] -> VT[bh][64][2048], with the key dimension
// XOR-swizzled per 16B block within each 64-key tile: block ^= d&7.
__global__ __launch_bounds__(256) void vtrans_kernel(
    const _Float16* __restrict__ V, _Float16* __restrict__ VT)
{
    __shared__ __align__(16) _Float16 T[64][72];
    const int tid = threadIdx.x;
    const int kt = blockIdx.x;      // 64-key chunk (0..31)
    const int bh = blockIdx.y;      // 0..31
    const int bi = bh >> 4, hi = bh & 15;
    const _Float16* Vh = V + (size_t)(bi * 2048 + hi * 128) * 1024 + kt * 4096;
    const int srow = tid >> 3, sblk = tid & 7;
    union { uint4 u; _Float16 h[8]; } a, b;
    a.u = *(const uint4*)(Vh + (2 * srow) * 64 + sblk * 8);
    b.u = *(const uint4*)(Vh + (2 * srow + 1) * 64 + sblk * 8);
    for (int j = 0; j < 8; j++) {
        union { unsigned u; _Float16 h[2]; } pk;
        pk.h[0] = a.h[j]; pk.h[1] = b.h[j];
        *(unsigned*)&T[sblk * 8 + j][2 * srow] = pk.u;
    }
    __syncthreads();
    const int d = tid >> 2, c = tid & 3;
    const int xr = d & 7;
    _Float16* outrow = VT + ((size_t)bh * 64 + d) * 2048 + kt * 64;
    *(uint4*)(outrow + ((2 * c)     ^ xr) * 8) = *(const uint4*)&T[d][c * 16];
    *(uint4*)(outrow + ((2 * c + 1) ^ xr) * 8) = *(const uint4*)&T[d][c * 16 + 8];
}

// P^T fragment assembly via permlane32_swap + permlane16_swap (v5-proven):
// r = {s16x[0], s16y[0], s16x[1], s16y[1]} = keys quad*8+0..7.
static __device__ __forceinline__ half8 assemble_p(uint2 a, uint2 b) {
    auto s32x = __builtin_amdgcn_permlane32_swap(a.x, b.x, false, false);
    auto s32y = __builtin_amdgcn_permlane32_swap(a.y, b.y, false, false);
    auto s16x = __builtin_amdgcn_permlane16_swap(s32x[0], s32x[1], false, false);
    auto s16y = __builtin_amdgcn_permlane16_swap(s32y[0], s32y[1], false, false);
    union { uint4 u; half8 h; } r;
    r.u.x = s16x[0];   // j0,j1
    r.u.y = s16y[0];   // j2,j3
    r.u.z = s16x[1];   // j4,j5
    r.u.w = s16y[1];   // j6,j7
    return r.h;
}

// ---------------- phase 3: flash attention, v7 (measured best: 47.5us) ----
// 512-thr blocks = two 4-wave KV-split groups; KVBLK=64, permlane P^T
// assembly, gll double-buffered K/V staging (zero staging VGPRs), one
// barrier per k-tile, setprio around MFMA clusters. 16 waves/CU.
__global__ __launch_bounds__(512, 4) void attn_kernel(
    const _Float16* __restrict__ Q, const _Float16* __restrict__ K,
    const _Float16* __restrict__ VT, _Float16* __restrict__ O)
{
    // per group: Ks[2][4096] | Vts[2][4096] = 16384 halfs; x2 groups = 64KB.
    // epilogue overlay: X 16384 halfs | L 2048 | Es 9216 -> 26624 <= 32768.
    __shared__ __align__(16) _Float16 smem[32768];

    const int tid  = threadIdx.x;
    const int g    = tid >> 8;            // KV-split group
    const int wg   = tid >> 6;            // global wave 0..7
    const int w    = wg & 3;              // wave within group
    const int lane = tid & 63;
    const int lrow = lane & 15, quad = lane >> 4;

    // XCD grouping: all 16 q-tiles of a head land on one XCD (4 heads/XCD)
    const int bid = blockIdx.x;
    const int bh  = (bid & 7) * 4 + (bid >> 7);
    const int qt  = (bid >> 3) & 15;
    const int bi = bh >> 4, hi = bh & 15;
    const size_t base = (size_t)(bi * 2048 + hi * 128) * 1024;
    const _Float16* Qh  = Q + base;
    const _Float16* Kh  = K + base + (size_t)g * 65536;          // +1024 keys
    const _Float16* VTh = VT + (size_t)bh * 131072 + g * 1024;   // +1024 keys

    _Float16* Ks0  = smem + g * 16384;          // [2][64][64]
    _Float16* Vts0 = smem + g * 16384 + 8192;   // [2][64][64]  ([d][key])

    // Q fragments: qrow = qt*128 + w*32 + nt*16 + lrow
    half8 qf[2][2];
    for (int nt = 0; nt < 2; nt++)
        for (int ks = 0; ks < 2; ks++)
            qf[nt][ks] = *(const half8*)(Qh + (qt * 128 + w * 32 + nt * 16 + lrow) * 64
                                          + ks * 32 + quad * 8);

    floatx4 oacc[4][2] = {};   // [dt][nt], O^T C-layout
    float lsum0 = 0.0f, lsum1 = 0.0f;

    // gll lane-linear staging sources (global images are pre-swizzled):
    const _Float16* klsrc = Kh + w * 1024 + lane * 8;
    const _Float16* vlsrc = VTh + (size_t)(w * 16 + (lane >> 3)) * 2048 + (lane & 7) * 8;

    auto stage = [&](int kt, int b) {
        const _Float16* ks = klsrc + kt * 4096;
        _Float16* kd = Ks0 + b * 4096 + w * 1024;
        __builtin_amdgcn_global_load_lds((const AS1 unsigned*)(const void*)ks,
                                         (AS3 unsigned*)(void*)kd, 16, 0, 0);
        __builtin_amdgcn_global_load_lds((const AS1 unsigned*)(const void*)(ks + 512),
                                         (AS3 unsigned*)(void*)(kd + 512), 16, 0, 0);
        const _Float16* vs = vlsrc + kt * 64;
        _Float16* vd = Vts0 + b * 4096 + w * 1024;
        __builtin_amdgcn_global_load_lds((const AS1 unsigned*)(const void*)vs,
                                         (AS3 unsigned*)(void*)vd, 16, 0, 0);
        __builtin_amdgcn_global_load_lds((const AS1 unsigned*)(const void*)(vs + 8 * 2048),
                                         (AS3 unsigned*)(void*)(vd + 512), 16, 0, 0);
    };

    const float LOG2E = 1.44269504f;
    const float OFF   = -8.65617025f;   // -6 * log2(e): p = e^(s-6)

    // preamble: stage tile 0 into buffer 0
    stage(0, 0);
    __syncthreads();   // vmcnt(0) drain -> buf0 ready

    for (int ktl = 0; ktl < 16; ktl++) {
        const int cur = ktl & 1;
        if (ktl < 15) stage(ktl + 1, cur ^ 1);   // in flight during compute
        const _Float16* Ksg  = Ks0 + cur * 4096;
        const _Float16* Vtsg = Vts0 + cur * 4096;
        for (int h = 0; h < 2; h++) {
            union { uint2 u; pkh2 h2[2]; } pA[2], pB[2];   // [k2]
            for (int k2 = 0; k2 < 2; k2++) {          // 16-key subtile
                const int kt4 = h * 2 + k2;
                floatx4 s0 = {}, s1 = {};
                __builtin_amdgcn_s_setprio(1);
                for (int ks = 0; ks < 2; ks++) {
                    half8 af = *(const half8*)&Ksg[(kt4 * 16 + lrow) * 64
                                 + (((ks * 4 + quad) ^ (lrow & 7)) * 8)];
                    s0 = __builtin_amdgcn_mfma_f32_16x16x32_f16(af, qf[0][ks], s0, 0, 0, 0);
                    s1 = __builtin_amdgcn_mfma_f32_16x16x32_f16(af, qf[1][ks], s1, 0, 0, 0);
                }
                __builtin_amdgcn_s_setprio(0);
                float p00 = __builtin_amdgcn_exp2f(fmaf(s0[0], LOG2E, OFF));
                float p01 = __builtin_amdgcn_exp2f(fmaf(s0[1], LOG2E, OFF));
                float p02 = __builtin_amdgcn_exp2f(fmaf(s0[2], LOG2E, OFF));
                float p03 = __builtin_amdgcn_exp2f(fmaf(s0[3], LOG2E, OFF));
                float p10 = __builtin_amdgcn_exp2f(fmaf(s1[0], LOG2E, OFF));
                float p11 = __builtin_amdgcn_exp2f(fmaf(s1[1], LOG2E, OFF));
                float p12 = __builtin_amdgcn_exp2f(fmaf(s1[2], LOG2E, OFF));
                float p13 = __builtin_amdgcn_exp2f(fmaf(s1[3], LOG2E, OFF));
                lsum0 += (p00 + p01) + (p02 + p03);
                lsum1 += (p10 + p11) + (p12 + p13);
                pA[k2].h2[0] = __builtin_amdgcn_cvt_pkrtz(p00, p01);
                pA[k2].h2[1] = __builtin_amdgcn_cvt_pkrtz(p02, p03);
                pB[k2].h2[0] = __builtin_amdgcn_cvt_pkrtz(p10, p11);
                pB[k2].h2[1] = __builtin_amdgcn_cvt_pkrtz(p12, p13);
            }
            // in-register P^T fragment assembly
            half8 bf0 = assemble_p(pA[0].u, pA[1].u);
            half8 bf1 = assemble_p(pB[0].u, pB[1].u);
            // O^T += V^T . P^T for this 32-key half
            __builtin_amdgcn_s_setprio(1);
            for (int dt = 0; dt < 4; dt++) {
                half8 av = *(const half8*)&Vtsg[(dt * 16 + lrow) * 64
                              + (((h * 4 + quad) ^ (lrow & 7)) * 8)];
                oacc[dt][0] = __builtin_amdgcn_mfma_f32_16x16x32_f16(av, bf0, oacc[dt][0], 0, 0, 0);
                oacc[dt][1] = __builtin_amdgcn_mfma_f32_16x16x32_f16(av, bf1, oacc[dt][1], 0, 0, 0);
            }
            __builtin_amdgcn_s_setprio(0);
        }
        __syncthreads();   // drains next-tile gll; frees buf cur for ktl+2
    }

    // ---- combine the two key-halves through LDS ----
    // X: [8 chunks][4 w][64 lane][4 f32] = 32KB over smem[0..16384) halfs.
    float* X = (float*)smem;
    float* L = (float*)(smem + 16384);   // 512 f32
    if (g == 1) {
        for (int dt = 0; dt < 4; dt++)
            for (int nt = 0; nt < 2; nt++)
                *(floatx4*)&X[((dt * 2 + nt) * 256 + w * 64 + lane) * 4] = oacc[dt][nt];
        L[(w * 64 + lane) * 2]     = lsum0;
        L[(w * 64 + lane) * 2 + 1] = lsum1;
    }
    __syncthreads();
    if (g == 0) {
        for (int dt = 0; dt < 4; dt++)
            for (int nt = 0; nt < 2; nt++)
                oacc[dt][nt] += *(const floatx4*)&X[((dt * 2 + nt) * 256 + w * 64 + lane) * 4];
        lsum0 += L[(w * 64 + lane) * 2];
        lsum1 += L[(w * 64 + lane) * 2 + 1];
        // reduce l over quads, normalize, transpose O^T -> O via LDS
        lsum0 += __shfl_xor(lsum0, 16, 64); lsum0 += __shfl_xor(lsum0, 32, 64);
        lsum1 += __shfl_xor(lsum1, 16, 64); lsum1 += __shfl_xor(lsum1, 32, 64);
        const float inv0 = 1.0f / lsum0, inv1 = 1.0f / lsum1;
        _Float16* Es = smem + 17408 + w * 2304;   // 32 rows x 72 per wave
        for (int dt = 0; dt < 4; dt++) {
            union { uint2 u; pkh2 h2[2]; } a0, a1;
            a0.h2[0] = __builtin_amdgcn_cvt_pkrtz(oacc[dt][0][0] * inv0, oacc[dt][0][1] * inv0);
            a0.h2[1] = __builtin_amdgcn_cvt_pkrtz(oacc[dt][0][2] * inv0, oacc[dt][0][3] * inv0);
            a1.h2[0] = __builtin_amdgcn_cvt_pkrtz(oacc[dt][1][0] * inv1, oacc[dt][1][1] * inv1);
            a1.h2[1] = __builtin_amdgcn_cvt_pkrtz(oacc[dt][1][2] * inv1, oacc[dt][1][3] * inv1);
            *(uint2*)&Es[lrow * 72 + dt * 16 + quad * 4]        = a0.u;
            *(uint2*)&Es[(16 + lrow) * 72 + dt * 16 + quad * 4] = a1.u;
        }
        const int rw = lane >> 1, hf = lane & 1;
        const size_t orow = (size_t)(bi * 2048 + qt * 128 + w * 32 + rw) * 1024
                            + hi * 64 + hf * 32;
        for (int i = 0; i < 4; i++)
            *(uint4*)(O + orow + i * 8) = *(const uint4*)&Es[rw * 72 + hf * 32 + i * 8];
    }
}

extern "C" void kernel_launch(void* const* d_in, const int* in_sizes, int n_in,
                              void* d_out, int out_size, void* d_ws, size_t ws_size,
                              hipStream_t stream) {
    const float* x    = (const float*)d_in[0];
    const float* wq   = (const float*)d_in[1];
    const float* bq   = (const float*)d_in[2];
    const float* wk   = (const float*)d_in[3];
    const float* bk   = (const float*)d_in[4];
    const float* wv   = (const float*)d_in[5];
    const float* bv   = (const float*)d_in[6];
    const float* wo   = (const float*)d_in[7];
    const float* bo   = (const float*)d_in[8];
    const float* cosT = (const float*)d_in[9];   // [3200][64]
    const float* sinT = (const float*)d_in[10];

    _Float16* ws   = (_Float16*)d_ws;
    _Float16* xb   = ws;                  // 4,194,304 (dead after qkv GEMM)
    _Float16* wqkv = xb + 4194304;        // 3,145,728 (wq|wk|wv)
    _Float16* wob  = wqkv + 3145728;      // 1,048,576
    _Float16* Qb   = wob + 1048576;       // 4,194,304
    _Float16* Kb   = Qb + 4194304;        // 4,194,304 (stored block-swizzled)
    _Float16* Vb   = Kb + 4194304;        // 4,194,304
    _Float16* Ob   = Vb + 4194304;        // 4,194,304  (total ~48 MB)
    _Float16* VTb  = xb;                  // aliases xb (consumed before vtrans)

    convert_kernel<<<8192, 256, 0, stream>>>(x, wq, wk, wv, wo, xb, wqkv, wob);
    // reference indexes cos/sin at row t=2048 (broadcast over all positions)
    gemm_kernel<true, 64, 128><<<dim3(64, 24), 256, 0, stream>>>(
        xb, wqkv, bq, bk, bv, cosT + 2048 * 64, sinT + 2048 * 64,
        Qb, Kb, Vb, nullptr);
    vtrans_kernel<<<dim3(32, 32), 256, 0, stream>>>(Vb, VTb);
    attn_kernel<<<dim3(512), 512, 0, stream>>>(Qb, Kb, VTb, Ob);
    gemm_kernel<false, 32, 128><<<dim3(128, 8), 256, 0, stream>>>(
        Ob, wob, bo, nullptr, nullptr, nullptr, nullptr,
        nullptr, nullptr, nullptr, (float*)d_out);
}

// Round 17
// 202.534 us; speedup vs baseline: 1.0712x; 1.0125x over previous
//
#include <hip/hip_runtime.h>

typedef _Float16 half8 __attribute__((ext_vector_type(8)));
typedef __fp16 pkh2 __attribute__((ext_vector_type(2)));   // cvt_pkrtz result type
typedef float floatx4 __attribute__((ext_vector_type(4)));

#define AS1 __attribute__((address_space(1)))
#define AS3 __attribute__((address_space(3)))

// Problem constants: B=2, T=2048, DM=1024, H=16, DK=64. BT = B*T = 4096 rows.
// Head slabs: reference reshape(b,h,t,d) makes each head a CONTIGUOUS
// [2048][64] slab at (bi*2048 + hi*128)*1024.

// ---------------- phase 1: f32 -> f16 conversion ----------------
// v16: 8 f32/thread (two float4 loads -> one 16B store), grid halved.
// All segment boundaries are multiples of 8 -> no straddling.
__global__ __launch_bounds__(256) void convert_kernel(
    const float* __restrict__ x, const float* __restrict__ wq,
    const float* __restrict__ wk, const float* __restrict__ wv,
    const float* __restrict__ wo,
    _Float16* __restrict__ xb, _Float16* __restrict__ wqkv,
    _Float16* __restrict__ wob)
{
    int i = (blockIdx.x * 256 + threadIdx.x) * 8;
    const float* src; _Float16* dst; int off;
    if (i < 4194304)      { src = x;  dst = xb;            off = i; }
    else if (i < 5242880) { src = wq; dst = wqkv;          off = i - 4194304; }
    else if (i < 6291456) { src = wk; dst = wqkv + 1048576; off = i - 5242880; }
    else if (i < 7340032) { src = wv; dst = wqkv + 2097152; off = i - 6291456; }
    else                  { src = wo; dst = wob;           off = i - 7340032; }
    float4 v0 = *(const float4*)(src + off);
    float4 v1 = *(const float4*)(src + off + 4);
    union { uint4 u; pkh2 h[4]; } o;
    o.h[0] = __builtin_amdgcn_cvt_pkrtz(v0.x, v0.y);
    o.h[1] = __builtin_amdgcn_cvt_pkrtz(v0.z, v0.w);
    o.h[2] = __builtin_amdgcn_cvt_pkrtz(v1.x, v1.y);
    o.h[3] = __builtin_amdgcn_cvt_pkrtz(v1.z, v1.w);
    *(uint4*)(dst + off) = o.u;
}

// ---------------- phase 2/4: GEMM  out = A @ W^T (+bias) ----------------
// Single-buffered 2-barrier m97 structure; cross-block TLP hides the
// staging drain. Measured tile optima (both directions probed):
//   QKV:  BM=64/BN=128, grid (64,24)  — BM=32 thrashes L2 (v14: FETCH 97MB)
//   proj: BM=32/BN=128, grid (128,8)  — grid was its occupancy limit (v13)
// XCD chunk-swizzle keeps each XCD's weight panels L2-resident. For
// seg==1 (K) the store column is XOR-swizzled at 16B-block granularity
// (block ^= (n>>6)&7) so attention can stage K tiles linearly.
template<bool QKV, int BM, int BN>
__global__ __launch_bounds__(256) void gemm_kernel(
    const _Float16* __restrict__ A, const _Float16* __restrict__ W,
    const float* __restrict__ b0, const float* __restrict__ b1,
    const float* __restrict__ b2,
    const float* __restrict__ cosr, const float* __restrict__ sinr,
    _Float16* __restrict__ O0, _Float16* __restrict__ O1,
    _Float16* __restrict__ O2, float* __restrict__ Of)
{
    constexpr int MT   = (BN == 128) ? BM / 32 : BM / 64;  // A frags per wave
    constexpr int AISS = BM / 32;   // A gll issues per wave (8 rows each)
    constexpr int WISS = BN / 32;   // W gll issues per wave
    __shared__ __align__(16) _Float16 As[BM * 64];
    __shared__ __align__(16) _Float16 Bs[BN * 64];
    const int tid  = threadIdx.x;
    const int lane = tid & 63, w = tid >> 6;
    const int lrow = lane & 15, quad = lane >> 4;
    const int wr = (BN == 128) ? (w & 1) * (BM / 2) : w * (BM / 4);
    const int wc = (BN == 128) ? (w >> 1) * 64 : 0;

    // XCD chunk-swizzle (bijective; grid size divisible by 8):
    const int nwg  = gridDim.x * gridDim.y;
    const int flat = blockIdx.y * gridDim.x + blockIdx.x;
    const int idx  = (flat & 7) * (nwg >> 3) + (flat >> 3);
    const int bx   = idx % gridDim.x;
    const int by   = idx / gridDim.x;

    const int arow0 = bx * BM;
    const int brow0 = by * BN;

    const int r8 = lane >> 3;                 // row within 8-row group
    const int gcol = ((lane & 7) ^ r8) * 8;   // swizzled global column (halfs)

    floatx4 acc[MT][4] = {};

    for (int kk = 0; kk < 1024; kk += 64) {
        __syncthreads();   // previous compute done reading LDS
        for (int u = 0; u < AISS; u++) {
            const int row = w * (8 * AISS) + u * 8;
            __builtin_amdgcn_global_load_lds(
                (const AS1 unsigned*)(const void*)(A + (size_t)(arow0 + row + r8) * 1024 + kk + gcol),
                (AS3 unsigned*)(void*)(As + row * 64), 16, 0, 0);
        }
        for (int u = 0; u < WISS; u++) {
            const int row = w * (8 * WISS) + u * 8;
            __builtin_amdgcn_global_load_lds(
                (const AS1 unsigned*)(const void*)(W + (size_t)(brow0 + row + r8) * 1024 + kk + gcol),
                (AS3 unsigned*)(void*)(Bs + row * 64), 16, 0, 0);
        }
        __syncthreads();   // vmcnt(0) drain inserted by compiler
        for (int ks = 0; ks < 2; ks++) {
            const int swz = ((ks * 4 + quad) ^ (lrow & 7)) * 8;
            half8 af[MT], bf[4];
            for (int mt = 0; mt < MT; mt++)
                af[mt] = *(const half8*)&As[(wr + mt * 16 + lrow) * 64 + swz];
            for (int nt = 0; nt < 4; nt++)
                bf[nt] = *(const half8*)&Bs[(wc + nt * 16 + lrow) * 64 + swz];
            for (int mt = 0; mt < MT; mt++)
                for (int nt = 0; nt < 4; nt++)
                    acc[mt][nt] = __builtin_amdgcn_mfma_f32_16x16x32_f16(
                        af[mt], bf[nt], acc[mt][nt], 0, 0, 0);
        }
    }

    if (QKV) {
        constexpr int CTS = 1024 / BN;   // col-tiles per segment
        const int seg = by / CTS;        // 0=Q 1=K 2=V
        const float* bias = seg == 0 ? b0 : (seg == 1 ? b1 : b2);
        _Float16* out = seg == 0 ? O0 : (seg == 1 ? O1 : O2);
        const int nbase = (by % CTS) * BN + wc;
        for (int nt = 0; nt < 4; nt++) {
            const int n = nbase + nt * 16 + lrow;
            const float bv = bias[n];
            const int dj = n & 63;
            const float cv = cosr[dj], sv = sinr[dj];
            const bool odd = (n & 1) != 0;
            // K storage swizzle: 16B block (bits 3..5 of n) ^= (n>>6)&7
            const int ns = (seg == 1)
                ? ((n & ~56) | ((((n >> 3) ^ (n >> 6)) & 7) << 3))
                : n;
            for (int mt = 0; mt < MT; mt++)
                for (int r = 0; r < 4; r++) {
                    float v = acc[mt][nt][r] + bv;
                    if (seg < 2) {
                        float p = __shfl_xor(v, 1, 64);
                        v = odd ? (v * cv + p * sv) : (v * cv - p * sv);
                    }
                    if (seg == 0) v *= 0.125f;
                    int row = arow0 + wr + mt * 16 + quad * 4 + r;
                    out[row * 1024 + ns] = (_Float16)v;
                }
        }
    } else {
        const int nbase = by * BN + wc;
        for (int nt = 0; nt < 4; nt++) {
            const int n = nbase + nt * 16 + lrow;
            const float bv = b0[n];
            for (int mt = 0; mt < MT; mt++)
                for (int r = 0; r < 4; r++) {
                    int row = arow0 + wr + mt * 16 + quad * 4 + r;
                    Of[row * 1024 + n] = acc[mt][nt][r] + bv;
                }
        }
    }
}

// ---------------- phase 2.5: one-shot V transpose ----------------
// V head chunk [2048][64] -> VT[bh][64][2048], with the key dimension
// XOR-swizzled per 16B block within each 64-key tile: block ^= d&7.
__global__ __launch_bounds__(256) void vtrans_kernel(
    const _Float16* __restrict__ V, _Float16* __restrict__ VT)
{
    __shared__ __align__(16) _Float16 T[64][72];
    const int tid = threadIdx.x;
    const int kt = blockIdx.x;      // 64-key chunk (0..31)
    const int bh = blockIdx.y;      // 0..31
    const int bi = bh >> 4, hi = bh & 15;
    const _Float16* Vh = V + (size_t)(bi * 2048 + hi * 128) * 1024 + kt * 4096;
    const int srow = tid >> 3, sblk = tid & 7;
    union { uint4 u; _Float16 h[8]; } a, b;
    a.u = *(const uint4*)(Vh + (2 * srow) * 64 + sblk * 8);
    b.u = *(const uint4*)(Vh + (2 * srow + 1) * 64 + sblk * 8);
    for (int j = 0; j < 8; j++) {
        union { unsigned u; _Float16 h[2]; } pk;
        pk.h[0] = a.h[j]; pk.h[1] = b.h[j];
        *(unsigned*)&T[sblk * 8 + j][2 * srow] = pk.u;
    }
    __syncthreads();
    const int d = tid >> 2, c = tid & 3;
    const int xr = d & 7;
    _Float16* outrow = VT + ((size_t)bh * 64 + d) * 2048 + kt * 64;
    *(uint4*)(outrow + ((2 * c)     ^ xr) * 8) = *(const uint4*)&T[d][c * 16];
    *(uint4*)(outrow + ((2 * c + 1) ^ xr) * 8) = *(const uint4*)&T[d][c * 16 + 8];
}

// P^T fragment assembly via permlane32_swap + permlane16_swap (v5-proven):
// r = {s16x[0], s16y[0], s16x[1], s16y[1]} = keys quad*8+0..7.
static __device__ __forceinline__ half8 assemble_p(uint2 a, uint2 b) {
    auto s32x = __builtin_amdgcn_permlane32_swap(a.x, b.x, false, false);
    auto s32y = __builtin_amdgcn_permlane32_swap(a.y, b.y, false, false);
    auto s16x = __builtin_amdgcn_permlane16_swap(s32x[0], s32x[1], false, false);
    auto s16y = __builtin_amdgcn_permlane16_swap(s32y[0], s32y[1], false, false);
    union { uint4 u; half8 h; } r;
    r.u.x = s16x[0];   // j0,j1
    r.u.y = s16y[0];   // j2,j3
    r.u.z = s16x[1];   // j4,j5
    r.u.w = s16y[1];   // j6,j7
    return r.h;
}

// ---------------- phase 3: flash attention, v7b ----------------
// v7 structure (512-thr blocks, two 4-wave KV-split groups, KVBLK=64,
// permlane P^T assembly, gll double-buffered staging, one barrier/kt)
// with setprio REMOVED: the per-kt __syncthreads locksteps all 8 waves
// (both groups), which is m190's null/negative regime for setprio —
// within-pipeline A/B vs v15's 47.8us decides.
__global__ __launch_bounds__(512, 4) void attn_kernel(
    const _Float16* __restrict__ Q, const _Float16* __restrict__ K,
    const _Float16* __restrict__ VT, _Float16* __restrict__ O)
{
    // per group: Ks[2][4096] | Vts[2][4096] = 16384 halfs; x2 groups = 64KB.
    // epilogue overlay: X 16384 halfs | L 2048 | Es 9216 -> 26624 <= 32768.
    __shared__ __align__(16) _Float16 smem[32768];

    const int tid  = threadIdx.x;
    const int g    = tid >> 8;            // KV-split group
    const int wg   = tid >> 6;            // global wave 0..7
    const int w    = wg & 3;              // wave within group
    const int lane = tid & 63;
    const int lrow = lane & 15, quad = lane >> 4;

    // XCD grouping: all 16 q-tiles of a head land on one XCD (4 heads/XCD)
    const int bid = blockIdx.x;
    const int bh  = (bid & 7) * 4 + (bid >> 7);
    const int qt  = (bid >> 3) & 15;
    const int bi = bh >> 4, hi = bh & 15;
    const size_t base = (size_t)(bi * 2048 + hi * 128) * 1024;
    const _Float16* Qh  = Q + base;
    const _Float16* Kh  = K + base + (size_t)g * 65536;          // +1024 keys
    const _Float16* VTh = VT + (size_t)bh * 131072 + g * 1024;   // +1024 keys

    _Float16* Ks0  = smem + g * 16384;          // [2][64][64]
    _Float16* Vts0 = smem + g * 16384 + 8192;   // [2][64][64]  ([d][key])

    // Q fragments: qrow = qt*128 + w*32 + nt*16 + lrow
    half8 qf[2][2];
    for (int nt = 0; nt < 2; nt++)
        for (int ks = 0; ks < 2; ks++)
            qf[nt][ks] = *(const half8*)(Qh + (qt * 128 + w * 32 + nt * 16 + lrow) * 64
                                          + ks * 32 + quad * 8);

    floatx4 oacc[4][2] = {};   // [dt][nt], O^T C-layout
    float lsum0 = 0.0f, lsum1 = 0.0f;

    // gll lane-linear staging sources (global images are pre-swizzled):
    const _Float16* klsrc = Kh + w * 1024 + lane * 8;
    const _Float16* vlsrc = VTh + (size_t)(w * 16 + (lane >> 3)) * 2048 + (lane & 7) * 8;

    auto stage = [&](int kt, int b) {
        const _Float16* ks = klsrc + kt * 4096;
        _Float16* kd = Ks0 + b * 4096 + w * 1024;
        __builtin_amdgcn_global_load_lds((const AS1 unsigned*)(const void*)ks,
                                         (AS3 unsigned*)(void*)kd, 16, 0, 0);
        __builtin_amdgcn_global_load_lds((const AS1 unsigned*)(const void*)(ks + 512),
                                         (AS3 unsigned*)(void*)(kd + 512), 16, 0, 0);
        const _Float16* vs = vlsrc + kt * 64;
        _Float16* vd = Vts0 + b * 4096 + w * 1024;
        __builtin_amdgcn_global_load_lds((const AS1 unsigned*)(const void*)vs,
                                         (AS3 unsigned*)(void*)vd, 16, 0, 0);
        __builtin_amdgcn_global_load_lds((const AS1 unsigned*)(const void*)(vs + 8 * 2048),
                                         (AS3 unsigned*)(void*)(vd + 512), 16, 0, 0);
    };

    const float LOG2E = 1.44269504f;
    const float OFF   = -8.65617025f;   // -6 * log2(e): p = e^(s-6)

    // preamble: stage tile 0 into buffer 0
    stage(0, 0);
    __syncthreads();   // vmcnt(0) drain -> buf0 ready

    for (int ktl = 0; ktl < 16; ktl++) {
        const int cur = ktl & 1;
        if (ktl < 15) stage(ktl + 1, cur ^ 1);   // in flight during compute
        const _Float16* Ksg  = Ks0 + cur * 4096;
        const _Float16* Vtsg = Vts0 + cur * 4096;
        for (int h = 0; h < 2; h++) {
            union { uint2 u; pkh2 h2[2]; } pA[2], pB[2];   // [k2]
            for (int k2 = 0; k2 < 2; k2++) {          // 16-key subtile
                const int kt4 = h * 2 + k2;
                floatx4 s0 = {}, s1 = {};
                for (int ks = 0; ks < 2; ks++) {
                    half8 af = *(const half8*)&Ksg[(kt4 * 16 + lrow) * 64
                                 + (((ks * 4 + quad) ^ (lrow & 7)) * 8)];
                    s0 = __builtin_amdgcn_mfma_f32_16x16x32_f16(af, qf[0][ks], s0, 0, 0, 0);
                    s1 = __builtin_amdgcn_mfma_f32_16x16x32_f16(af, qf[1][ks], s1, 0, 0, 0);
                }
                float p00 = __builtin_amdgcn_exp2f(fmaf(s0[0], LOG2E, OFF));
                float p01 = __builtin_amdgcn_exp2f(fmaf(s0[1], LOG2E, OFF));
                float p02 = __builtin_amdgcn_exp2f(fmaf(s0[2], LOG2E, OFF));
                float p03 = __builtin_amdgcn_exp2f(fmaf(s0[3], LOG2E, OFF));
                float p10 = __builtin_amdgcn_exp2f(fmaf(s1[0], LOG2E, OFF));
                float p11 = __builtin_amdgcn_exp2f(fmaf(s1[1], LOG2E, OFF));
                float p12 = __builtin_amdgcn_exp2f(fmaf(s1[2], LOG2E, OFF));
                float p13 = __builtin_amdgcn_exp2f(fmaf(s1[3], LOG2E, OFF));
                lsum0 += (p00 + p01) + (p02 + p03);
                lsum1 += (p10 + p11) + (p12 + p13);
                pA[k2].h2[0] = __builtin_amdgcn_cvt_pkrtz(p00, p01);
                pA[k2].h2[1] = __builtin_amdgcn_cvt_pkrtz(p02, p03);
                pB[k2].h2[0] = __builtin_amdgcn_cvt_pkrtz(p10, p11);
                pB[k2].h2[1] = __builtin_amdgcn_cvt_pkrtz(p12, p13);
            }
            // in-register P^T fragment assembly
            half8 bf0 = assemble_p(pA[0].u, pA[1].u);
            half8 bf1 = assemble_p(pB[0].u, pB[1].u);
            // O^T += V^T . P^T for this 32-key half
            for (int dt = 0; dt < 4; dt++) {
                half8 av = *(const half8*)&Vtsg[(dt * 16 + lrow) * 64
                              + (((h * 4 + quad) ^ (lrow & 7)) * 8)];
                oacc[dt][0] = __builtin_amdgcn_mfma_f32_16x16x32_f16(av, bf0, oacc[dt][0], 0, 0, 0);
                oacc[dt][1] = __builtin_amdgcn_mfma_f32_16x16x32_f16(av, bf1, oacc[dt][1], 0, 0, 0);
            }
        }
        __syncthreads();   // drains next-tile gll; frees buf cur for ktl+2
    }

    // ---- combine the two key-halves through LDS ----
    // X: [8 chunks][4 w][64 lane][4 f32] = 32KB over smem[0..16384) halfs.
    float* X = (float*)smem;
    float* L = (float*)(smem + 16384);   // 512 f32
    if (g == 1) {
        for (int dt = 0; dt < 4; dt++)
            for (int nt = 0; nt < 2; nt++)
                *(floatx4*)&X[((dt * 2 + nt) * 256 + w * 64 + lane) * 4] = oacc[dt][nt];
        L[(w * 64 + lane) * 2]     = lsum0;
        L[(w * 64 + lane) * 2 + 1] = lsum1;
    }
    __syncthreads();
    if (g == 0) {
        for (int dt = 0; dt < 4; dt++)
            for (int nt = 0; nt < 2; nt++)
                oacc[dt][nt] += *(const floatx4*)&X[((dt * 2 + nt) * 256 + w * 64 + lane) * 4];
        lsum0 += L[(w * 64 + lane) * 2];
        lsum1 += L[(w * 64 + lane) * 2 + 1];
        // reduce l over quads, normalize, transpose O^T -> O via LDS
        lsum0 += __shfl_xor(lsum0, 16, 64); lsum0 += __shfl_xor(lsum0, 32, 64);
        lsum1 += __shfl_xor(lsum1, 16, 64); lsum1 += __shfl_xor(lsum1, 32, 64);
        const float inv0 = 1.0f / lsum0, inv1 = 1.0f / lsum1;
        _Float16* Es = smem + 17408 + w * 2304;   // 32 rows x 72 per wave
        for (int dt = 0; dt < 4; dt++) {
            union { uint2 u; pkh2 h2[2]; } a0, a1;
            a0.h2[0] = __builtin_amdgcn_cvt_pkrtz(oacc[dt][0][0] * inv0, oacc[dt][0][1] * inv0);
            a0.h2[1] = __builtin_amdgcn_cvt_pkrtz(oacc[dt][0][2] * inv0, oacc[dt][0][3] * inv0);
            a1.h2[0] = __builtin_amdgcn_cvt_pkrtz(oacc[dt][1][0] * inv1, oacc[dt][1][1] * inv1);
            a1.h2[1] = __builtin_amdgcn_cvt_pkrtz(oacc[dt][1][2] * inv1, oacc[dt][1][3] * inv1);
            *(uint2*)&Es[lrow * 72 + dt * 16 + quad * 4]        = a0.u;
            *(uint2*)&Es[(16 + lrow) * 72 + dt * 16 + quad * 4] = a1.u;
        }
        const int rw = lane >> 1, hf = lane & 1;
        const size_t orow = (size_t)(bi * 2048 + qt * 128 + w * 32 + rw) * 1024
                            + hi * 64 + hf * 32;
        for (int i = 0; i < 4; i++)
            *(uint4*)(O + orow + i * 8) = *(const uint4*)&Es[rw * 72 + hf * 32 + i * 8];
    }
}

extern "C" void kernel_launch(void* const* d_in, const int* in_sizes, int n_in,
                              void* d_out, int out_size, void* d_ws, size_t ws_size,
                              hipStream_t stream) {
    const float* x    = (const float*)d_in[0];
    const float* wq   = (const float*)d_in[1];
    const float* bq   = (const float*)d_in[2];
    const float* wk   = (const float*)d_in[3];
    const float* bk   = (const float*)d_in[4];
    const float* wv   = (const float*)d_in[5];
    const float* bv   = (const float*)d_in[6];
    const float* wo   = (const float*)d_in[7];
    const float* bo   = (const float*)d_in[8];
    const float* cosT = (const float*)d_in[9];   // [3200][64]
    const float* sinT = (const float*)d_in[10];

    _Float16* ws   = (_Float16*)d_ws;
    _Float16* xb   = ws;                  // 4,194,304 (dead after qkv GEMM)
    _Float16* wqkv = xb + 4194304;        // 3,145,728 (wq|wk|wv)
    _Float16* wob  = wqkv + 3145728;      // 1,048,576
    _Float16* Qb   = wob + 1048576;       // 4,194,304
    _Float16* Kb   = Qb + 4194304;        // 4,194,304 (stored block-swizzled)
    _Float16* Vb   = Kb + 4194304;        // 4,194,304
    _Float16* Ob   = Vb + 4194304;        // 4,194,304  (total ~48 MB)
    _Float16* VTb  = xb;                  // aliases xb (consumed before vtrans)

    convert_kernel<<<4096, 256, 0, stream>>>(x, wq, wk, wv, wo, xb, wqkv, wob);
    // reference indexes cos/sin at row t=2048 (broadcast over all positions)
    gemm_kernel<true, 64, 128><<<dim3(64, 24), 256, 0, stream>>>(
        xb, wqkv, bq, bk, bv, cosT + 2048 * 64, sinT + 2048 * 64,
        Qb, Kb, Vb, nullptr);
    vtrans_kernel<<<dim3(32, 32), 256, 0, stream>>>(Vb, VTb);
    attn_kernel<<<dim3(512), 512, 0, stream>>>(Qb, Kb, VTb, Ob);
    gemm_kernel<false, 32, 128><<<dim3(128, 8), 256, 0, stream>>>(
        Ob, wob, bo, nullptr, nullptr, nullptr, nullptr,
        nullptr, nullptr, nullptr, (float*)d_out);
}